// Round 4
// baseline (772.676 us; speedup 1.0000x reference)
//
#include <hip/hip_runtime.h>
#include <hip/hip_bf16.h>
#include <stdint.h>
#include <stddef.h>

// B=2, T=2048, D=2048, H=16, DH=128, F=8192, M=B*T=4096
using bf16_t = __hip_bfloat16;
typedef __attribute__((ext_vector_type(8))) short short8;
typedef __attribute__((ext_vector_type(4))) float f32x4;

__device__ __forceinline__ void gload_lds16(const void* g, void* l) {
  __builtin_amdgcn_global_load_lds((const __attribute__((address_space(1))) void*)g,
                                   (__attribute__((address_space(3))) void*)l,
                                   16, 0, 0);
}

// ---------- transpose + f32->bf16 convert: out[N][K] = in[K][N] ----------
__global__ __launch_bounds__(256) void k_transpose_cvt(const float* __restrict__ in,
                                                       bf16_t* __restrict__ out,
                                                       int K, int N) {
  __shared__ float tile[64][65];
  int n0 = blockIdx.x * 64, k0 = blockIdx.y * 64;
  int t = threadIdx.x;
#pragma unroll
  for (int i = 0; i < 16; ++i) {
    int idx = t + i * 256;
    int kk = idx >> 6, nn = idx & 63;
    tile[kk][nn] = in[(size_t)(k0 + kk) * N + n0 + nn];
  }
  __syncthreads();
#pragma unroll
  for (int i = 0; i < 16; ++i) {
    int idx = t + i * 256;
    int nn = idx >> 6, kk = idx & 63;
    out[(size_t)(n0 + nn) * K + k0 + kk] = __float2bfloat16(tile[kk][nn]);
  }
}

// ---------- layernorm f32 -> bf16, one block per row of 2048 ----------
__global__ __launch_bounds__(256) void k_layernorm(const float* __restrict__ x,
                                                   const float* __restrict__ gam,
                                                   const float* __restrict__ bet,
                                                   bf16_t* __restrict__ out) {
  int row = blockIdx.x, t = threadIdx.x;
  const float4* xr = (const float4*)(x + (size_t)row * 2048);
  float4 a = xr[t], b = xr[t + 256];
  float s  = a.x + a.y + a.z + a.w + b.x + b.y + b.z + b.w;
  float s2 = a.x*a.x + a.y*a.y + a.z*a.z + a.w*a.w
           + b.x*b.x + b.y*b.y + b.z*b.z + b.w*b.w;
#pragma unroll
  for (int off = 32; off >= 1; off >>= 1) {
    s  += __shfl_xor(s, off);
    s2 += __shfl_xor(s2, off);
  }
  __shared__ float red[8];
  if ((t & 63) == 0) { red[t >> 6] = s; red[4 + (t >> 6)] = s2; }
  __syncthreads();
  float S  = red[0] + red[1] + red[2] + red[3];
  float S2 = red[4] + red[5] + red[6] + red[7];
  float mu = S * (1.0f / 2048.0f);
  float var = S2 * (1.0f / 2048.0f) - mu * mu;
  float rstd = rsqrtf(var + 1e-6f);
  const float4* gv = (const float4*)gam;
  const float4* bv = (const float4*)bet;
  float4 g1 = gv[t], g2 = gv[t + 256], c1 = bv[t], c2 = bv[t + 256];
  bf16_t* orow = out + (size_t)row * 2048;
  orow[4*t + 0]    = __float2bfloat16((a.x - mu) * rstd * g1.x + c1.x);
  orow[4*t + 1]    = __float2bfloat16((a.y - mu) * rstd * g1.y + c1.y);
  orow[4*t + 2]    = __float2bfloat16((a.z - mu) * rstd * g1.z + c1.z);
  orow[4*t + 3]    = __float2bfloat16((a.w - mu) * rstd * g1.w + c1.w);
  orow[1024 + 4*t + 0] = __float2bfloat16((b.x - mu) * rstd * g2.x + c2.x);
  orow[1024 + 4*t + 1] = __float2bfloat16((b.y - mu) * rstd * g2.y + c2.y);
  orow[1024 + 4*t + 2] = __float2bfloat16((b.z - mu) * rstd * g2.z + c2.z);
  orow[1024 + 4*t + 3] = __float2bfloat16((b.w - mu) * rstd * g2.w + c2.w);
}

// ---------- counted-vmcnt 4-phase GEMM: C[M,N] = A[M,K] x Bt[N,K] (bf16) ----------
// BM=256, BK=64, BN_ in {128,256}. 512 threads = 8 waves (2 M x 4 N), per-wave C = 128 x WN.
// Per K-step: 4 quadrant phases; each phase stages one QUARTER of K-step t+1 into the
// free dbuf (issued in consumption order A-lo, B-lo, B-hi, A-hi) and closes with a
// COUNTED vmcnt so loads stay in flight across the K-step boundary (T3+T4). T2 XOR
// swizzle on both sides (pre-swizzled global source, swizzled ds_read). T5 setprio.
// EPI: 0 = bf16 out + bias ; 1 = bf16 + bias + gelu ; 2 = f32 + bias + residual.
template <int EPI, int BN_>
__global__ __launch_bounds__(512, 2) void k_gemm2(const bf16_t* __restrict__ A,
                                                  const bf16_t* __restrict__ Bt,
                                                  const float* __restrict__ bias,
                                                  bf16_t* __restrict__ Cb,
                                                  float* __restrict__ Cf,
                                                  int Ndim, int Kdim) {
  constexpr int WN = BN_ / 4;                 // per-wave N width: 64 or 32
  constexpr int NF = WN / 16;                 // n-frags per wave: 4 or 2
  constexpr int NQ = NF / 2;                  // n-frags per quadrant: 2 or 1
  constexpr int A_L = 2;                      // A-quarter loads/thread
  constexpr int B_L = (BN_ == 256) ? 2 : 1;   // B-quarter loads/thread
  constexpr int W_AB = A_L + B_L;             // steady waits
  constexpr int W_2A = 2 * A_L;
  __shared__ __align__(16) bf16_t Abuf[2][256 * 64];
  __shared__ __align__(16) bf16_t Bbuf[2][BN_ * 64];
  int nwg = gridDim.x;
  int orig = blockIdx.x;
  int wg = (orig & 7) * (nwg >> 3) + (orig >> 3);   // bijective (grids % 8 == 0)
  int m0 = (wg & 15) * 256;
  int n0 = (wg >> 4) * BN_;
  int tid = threadIdx.x;
  int w = tid >> 6, lane = tid & 63;
  int lr = lane & 15, lk = lane >> 4;
  int wr = w >> 2, wc = w & 3;
  const int NT = Kdim >> 6;
  const bf16_t* Ag = A + (size_t)m0 * Kdim;
  const bf16_t* Bg = Bt + (size_t)n0 * Kdim;

  f32x4 acc[8][NF];
#pragma unroll
  for (int i = 0; i < 8; ++i)
#pragma unroll
    for (int j = 0; j < NF; ++j) acc[i][j] = (f32x4){0.f, 0.f, 0.f, 0.f};
  short8 af[4][2], bq[NF][2];

  // half=0: A rows {0-63,128-191}; half=1: +64 (matches phase consumption order)
  auto stageA = [&](int buf, int kt, int half) {
#pragma unroll
    for (int l = 0; l < A_L; ++l) {
      int idx = l * 512 + tid;
      int qr = idx >> 3, c16 = idx & 7;
      int prow = (qr & 63) + ((qr >> 6) << 7) + half * 64;
      gload_lds16(Ag + (size_t)prow * Kdim + kt * 64 + ((c16 ^ (prow & 7)) << 3),
                  &Abuf[buf][(prow * 8 + c16) * 8]);
    }
  };
  // half=0: B rows in per-wave n-lo stripes; half=1: n-hi stripes
  auto stageB = [&](int buf, int kt, int half) {
#pragma unroll
    for (int l = 0; l < B_L; ++l) {
      int idx = l * 512 + tid;
      int qr = idx >> 3, c16 = idx & 7;
      int prow;
      if constexpr (BN_ == 256) prow = (qr & 31) + ((qr >> 5) << 6) + half * 32;
      else                      prow = (qr & 15) + ((qr >> 4) << 5) + half * 16;
      gload_lds16(Bg + (size_t)prow * Kdim + kt * 64 + ((c16 ^ (prow & 7)) << 3),
                  &Bbuf[buf][(prow * 8 + c16) * 8]);
    }
  };
  auto readA = [&](int buf, int mbase) {
#pragma unroll
    for (int mf = 0; mf < 4; ++mf)
#pragma unroll
      for (int ks = 0; ks < 2; ++ks) {
        int row = wr * 128 + (mbase + mf) * 16 + lr;
        int c16 = (ks * 4 + lk) ^ (lr & 7);
        af[mf][ks] = *(const short8*)&Abuf[buf][row * 64 + c16 * 8];
      }
  };
  auto readB = [&](int buf, int nbase) {
#pragma unroll
    for (int nf = 0; nf < NQ; ++nf)
#pragma unroll
      for (int ks = 0; ks < 2; ++ks) {
        int row = wc * WN + (nbase + nf) * 16 + lr;
        int c16 = (ks * 4 + lk) ^ (lr & 7);
        bq[nbase + nf][ks] = *(const short8*)&Bbuf[buf][row * 64 + c16 * 8];
      }
  };
  auto mmac = [&](int mbase, int nbase) {
#pragma unroll
    for (int ks = 0; ks < 2; ++ks)
#pragma unroll
      for (int mf = 0; mf < 4; ++mf)
#pragma unroll
        for (int nf = 0; nf < NQ; ++nf)
          acc[mbase + mf][nbase + nf] = __builtin_amdgcn_mfma_f32_16x16x32_bf16(
              af[mf][ks], bq[nbase + nf][ks], acc[mbase + mf][nbase + nf], 0, 0, 0);
  };

#define BARRIER()  asm volatile("s_barrier" ::: "memory")
#define LGKM0()    do { asm volatile("s_waitcnt lgkmcnt(0)" ::: "memory"); __builtin_amdgcn_sched_barrier(0); } while (0)
#define VM(N)      asm volatile("s_waitcnt vmcnt(%0)" :: "i"(N) : "memory")

  // prologue: stage all 4 quarters of K-step 0 in consumption order
  stageA(0, 0, 0); stageB(0, 0, 0); stageB(0, 0, 1); stageA(0, 0, 1);
  VM(W_AB);
  BARRIER();

  for (int t = 0; t < NT - 1; ++t) {
    int cur = t & 1, nxt = cur ^ 1;
    // phase 0: quadrant (m-lo, n-lo); stage A-lo of t+1
    readA(cur, 0); readB(cur, 0);
    stageA(nxt, t + 1, 0);
    BARRIER(); LGKM0();
    __builtin_amdgcn_s_setprio(1); mmac(0, 0); __builtin_amdgcn_s_setprio(0);
    VM(W_2A); BARRIER();
    // phase 1: quadrant (m-lo, n-hi); stage B-lo of t+1
    readB(cur, NQ);
    stageB(nxt, t + 1, 0);
    BARRIER(); LGKM0();
    __builtin_amdgcn_s_setprio(1); mmac(0, NQ); __builtin_amdgcn_s_setprio(0);
    VM(W_AB); BARRIER();
    // phase 2: quadrant (m-hi, n-hi); stage B-hi of t+1
    readA(cur, 4);
    stageB(nxt, t + 1, 1);
    BARRIER(); LGKM0();
    __builtin_amdgcn_s_setprio(1); mmac(4, NQ); __builtin_amdgcn_s_setprio(0);
    BARRIER();
    // phase 3: quadrant (m-hi, n-lo); stage A-hi of t+1
    stageA(nxt, t + 1, 1);
    BARRIER();
    __builtin_amdgcn_s_setprio(1); mmac(4, 0); __builtin_amdgcn_s_setprio(0);
    VM(W_AB); BARRIER();
  }
  {  // final K-step (peeled; no staging, tight waits)
    int cur = (NT - 1) & 1;
    readA(cur, 0); readB(cur, 0);
    BARRIER(); LGKM0();
    mmac(0, 0);
    VM(A_L); BARRIER();
    readB(cur, NQ);
    BARRIER(); LGKM0();
    mmac(0, NQ);
    VM(0); BARRIER();
    readA(cur, 4);
    LGKM0();
    mmac(4, NQ);
    mmac(4, 0);
  }
#undef BARRIER
#undef LGKM0
#undef VM

  // epilogue
#pragma unroll
  for (int mf = 0; mf < 8; ++mf) {
#pragma unroll
    for (int nf = 0; nf < NF; ++nf) {
#pragma unroll
      for (int r = 0; r < 4; ++r) {
        int rw = m0 + wr * 128 + mf * 16 + lk * 4 + r;
        int cl = n0 + wc * WN + nf * 16 + lr;
        float v = acc[mf][nf][r] + bias[cl];
        size_t gi = (size_t)rw * Ndim + cl;
        if (EPI == 0) {
          Cb[gi] = __float2bfloat16(v);
        } else if (EPI == 1) {
          float u = v * (v * v * 0.044715f + 1.0f) * 0.7978845608028654f;
          float gl = 0.5f * v * (1.0f + tanhf(u));
          Cb[gi] = __float2bfloat16(gl);
        } else {
          Cf[gi] = v + Cf[gi];
        }
      }
    }
  }
}

// ---------- transpose V slice of qkv into vT[b][h][dh][t] ----------
__global__ __launch_bounds__(256) void k_transpose_v(const bf16_t* __restrict__ qkv,
                                                     bf16_t* __restrict__ vT) {
  __shared__ bf16_t tile[64][72];
  int bid = blockIdx.x;
  int tt = bid & 31;
  int dt = (bid >> 5) & 1;
  int h  = (bid >> 6) & 15;
  int b  = bid >> 10;
  int t0 = tt * 64, d0 = dt * 64;
  int t = threadIdx.x;
  const bf16_t* src = qkv + (size_t)(b * 2048) * 6144 + 4096 + h * 128;
#pragma unroll
  for (int i = 0; i < 16; ++i) {
    int idx = t + i * 256;
    int rr = idx >> 6, cc = idx & 63;          // rr: t-dim, cc: d-dim
    tile[rr][cc] = src[(size_t)(t0 + rr) * 6144 + d0 + cc];
  }
  __syncthreads();
  bf16_t* dst = vT + (size_t)(b * 16 + h) * 128 * 2048;
#pragma unroll
  for (int i = 0; i < 16; ++i) {
    int idx = t + i * 256;
    int rr = idx >> 6, cc = idx & 63;          // rr: d-dim, cc: t-dim
    dst[(size_t)(d0 + rr) * 2048 + t0 + cc] = tile[cc][rr];
  }
}

// ---------- causal flash attention + residual add: out = x + softmax(QK^T/sqrt(dh))V ----------
// One wave owns 32 q-rows (2x16 fragments). KBLK=32. 512 blocks x 4 waves.
// Block j: bh = j&31, cq = j>>5; waves get q-chunks {cq, 63-cq, 31-cq, 32+cq}.
__global__ __launch_bounds__(256, 2) void k_attn(const bf16_t* __restrict__ qkv,
                                                 const bf16_t* __restrict__ vT,
                                                 const float* __restrict__ x,
                                                 float* __restrict__ out) {
  __shared__ __align__(16) bf16_t Pl[4][32][40];   // per-wave P bounce, stride 40
  int j = blockIdx.x;
  int bh = j & 31;
  int cq = j >> 5;                                  // 0..15
  int b = bh >> 4, h = bh & 15;
  int w = threadIdx.x >> 6, lane = threadIdx.x & 63;
  int lr = lane & 15, lk = lane >> 4;
  int c = (w == 0) ? cq : (w == 1) ? (63 - cq) : (w == 2) ? (31 - cq) : (32 + cq);
  int q0 = c * 32;                                  // this wave's 32 q-rows
  const bf16_t* qb = qkv + (size_t)(b * 2048) * 6144 + h * 128;
  const bf16_t* kb = qb + 2048;
  const bf16_t* vb = vT + (size_t)(b * 16 + h) * 128 * 2048;
  short8 qf[2][4];
#pragma unroll
  for (int qg = 0; qg < 2; ++qg)
#pragma unroll
    for (int d4 = 0; d4 < 4; ++d4)
      qf[qg][d4] = *(const short8*)(qb + (size_t)(q0 + qg * 16 + lr) * 6144 + d4 * 32 + lk * 8);
  float m[2][4], l[2][4];
#pragma unroll
  for (int qg = 0; qg < 2; ++qg)
#pragma unroll
    for (int r = 0; r < 4; ++r) { m[qg][r] = -1e30f; l[qg][r] = 0.f; }
  f32x4 o[2][8] = {};
  int nkt = c + 1;
  const float sc = 0.08838834764831845f;           // 1/sqrt(128)
  for (int kt = 0; kt < nkt; ++kt) {
    int tk0 = kt * 32;
    short8 vf[8];
#pragma unroll
    for (int d8 = 0; d8 < 8; ++d8)
      vf[d8] = *(const short8*)(vb + (size_t)(d8 * 16 + lr) * 2048 + tk0 + lk * 8);
    short8 kf[2][4];
#pragma unroll
    for (int nt = 0; nt < 2; ++nt)
#pragma unroll
      for (int d4 = 0; d4 < 4; ++d4)
        kf[nt][d4] = *(const short8*)(kb + (size_t)(tk0 + nt * 16 + lr) * 6144 + d4 * 32 + lk * 8);
    f32x4 s[2][2] = {};
#pragma unroll
    for (int d4 = 0; d4 < 4; ++d4)
#pragma unroll
      for (int qg = 0; qg < 2; ++qg)
#pragma unroll
        for (int nt = 0; nt < 2; ++nt)
          s[qg][nt] = __builtin_amdgcn_mfma_f32_16x16x32_bf16(qf[qg][d4], kf[nt][d4], s[qg][nt], 0, 0, 0);
#pragma unroll
    for (int qg = 0; qg < 2; ++qg) {
      float sv[2][4], mt[4];
#pragma unroll
      for (int r = 0; r < 4; ++r) {
        int qr = q0 + qg * 16 + lk * 4 + r;
#pragma unroll
        for (int nt = 0; nt < 2; ++nt) {
          float v = s[qg][nt][r] * sc;
          int kc = tk0 + nt * 16 + lr;
          sv[nt][r] = (kc > qr) ? -1e30f : v;
        }
        mt[r] = fmaxf(sv[0][r], sv[1][r]);
      }
#pragma unroll
      for (int off = 1; off < 16; off <<= 1)
#pragma unroll
        for (int r = 0; r < 4; ++r) mt[r] = fmaxf(mt[r], __shfl_xor(mt[r], off));
      float alpha[4], rs[4];
#pragma unroll
      for (int r = 0; r < 4; ++r) {
        float mn = fmaxf(m[qg][r], mt[r]);
        alpha[r] = __expf(m[qg][r] - mn);
        m[qg][r] = mn;
      }
#pragma unroll
      for (int r = 0; r < 4; ++r) {
        float p0 = __expf(sv[0][r] - m[qg][r]);
        float p1 = __expf(sv[1][r] - m[qg][r]);
        rs[r] = p0 + p1;
        Pl[w][qg * 16 + lk * 4 + r][lr]      = __float2bfloat16(p0);
        Pl[w][qg * 16 + lk * 4 + r][16 + lr] = __float2bfloat16(p1);
      }
#pragma unroll
      for (int off = 1; off < 16; off <<= 1)
#pragma unroll
        for (int r = 0; r < 4; ++r) rs[r] += __shfl_xor(rs[r], off);
#pragma unroll
      for (int r = 0; r < 4; ++r) l[qg][r] = l[qg][r] * alpha[r] + rs[r];
#pragma unroll
      for (int d8 = 0; d8 < 8; ++d8)
#pragma unroll
        for (int r = 0; r < 4; ++r) o[qg][d8][r] *= alpha[r];
    }
    asm volatile("s_waitcnt lgkmcnt(0)" ::: "memory");
    short8 pf[2];
#pragma unroll
    for (int qg = 0; qg < 2; ++qg)
      pf[qg] = *(const short8*)(&Pl[w][qg * 16 + lr][lk * 8]);
#pragma unroll
    for (int d8 = 0; d8 < 8; ++d8)
#pragma unroll
      for (int qg = 0; qg < 2; ++qg)
        o[qg][d8] = __builtin_amdgcn_mfma_f32_16x16x32_bf16(pf[qg], vf[d8], o[qg][d8], 0, 0, 0);
  }
#pragma unroll
  for (int qg = 0; qg < 2; ++qg)
#pragma unroll
    for (int d8 = 0; d8 < 8; ++d8)
#pragma unroll
      for (int r = 0; r < 4; ++r) {
        int qr = q0 + qg * 16 + lk * 4 + r;
        int cl = h * 128 + d8 * 16 + lr;
        size_t gi = (size_t)(b * 2048 + qr) * 2048 + cl;
        out[gi] = x[gi] + o[qg][d8][r] / l[qg][r];
      }
}

extern "C" void kernel_launch(void* const* d_in, const int* in_sizes, int n_in,
                              void* d_out, int out_size, void* d_ws, size_t ws_size,
                              hipStream_t stream) {
  const float* x    = (const float*)d_in[0];
  const float* ln1s = (const float*)d_in[1];
  const float* ln1b = (const float*)d_in[2];
  const float* wqkv = (const float*)d_in[3];
  const float* bqkv = (const float*)d_in[4];
  const float* ln2s = (const float*)d_in[5];
  const float* ln2b = (const float*)d_in[6];
  const float* w1   = (const float*)d_in[7];
  const float* b1   = (const float*)d_in[8];
  const float* w2   = (const float*)d_in[9];
  const float* b2   = (const float*)d_in[10];
  float* out = (float*)d_out;
  char* ws = (char*)d_ws;

  // ws layout (bytes); r/vT share one region (disjoint lifetimes), wqkvT aliases h.
  bf16_t* r     = (bf16_t*)(ws + 0);              // 16,777,216  [4096][2048]
  bf16_t* vT    = (bf16_t*)(ws + 0);              // same region [2][16][128][2048]
  bf16_t* qkv   = (bf16_t*)(ws + 16777216);       // 50,331,648  [4096][6144]
  bf16_t* w1T   = (bf16_t*)(ws + 67108864);       // 33,554,432  [8192][2048]
  bf16_t* w2T   = (bf16_t*)(ws + 100663296);      // 33,554,432  [2048][8192]
  bf16_t* h     = (bf16_t*)(ws + 134217728);      // 67,108,864  [4096][8192]
  bf16_t* wqkvT = (bf16_t*)(ws + 134217728);      // 25,165,824  [6144][2048] (dead before h is written)
  // total required: 201,326,592 bytes

  // weight transposes (f32 [K][N] -> bf16 [N][K])
  k_transpose_cvt<<<dim3(96, 32),  256, 0, stream>>>(wqkv, wqkvT, 2048, 6144);
  k_transpose_cvt<<<dim3(128, 32), 256, 0, stream>>>(w1,   w1T,   2048, 8192);
  k_transpose_cvt<<<dim3(32, 128), 256, 0, stream>>>(w2,   w2T,   8192, 2048);
  // LN1
  k_layernorm<<<4096, 256, 0, stream>>>(x, ln1s, ln1b, r);
  // QKV projection: M=4096, N=6144, K=2048 -> 16 x 24 = 384 blocks
  k_gemm2<0, 256><<<384, 512, 0, stream>>>(r, wqkvT, bqkv, qkv, nullptr, 6144, 2048);
  // V transpose for PV operand
  k_transpose_v<<<2048, 256, 0, stream>>>(qkv, vT);
  // attention + residual (writes every element of d_out)
  k_attn<<<512, 256, 0, stream>>>(qkv, vT, x, out);
  // LN2 on x2 = d_out
  k_layernorm<<<4096, 256, 0, stream>>>(out, ln2s, ln2b, r);
  // MLP1: M=4096, N=8192, K=2048 -> 16 x 32 = 512 blocks (2/CU)
  k_gemm2<1, 256><<<512, 512, 0, stream>>>(r, w1T, b1, h, nullptr, 8192, 2048);
  // MLP2: M=4096, N=2048, K=8192 -> 16 x 16 = 256 blocks (1/CU)
  k_gemm2<2, 128><<<256, 512, 0, stream>>>(h, w2T, b2, nullptr, out, 2048, 8192);
}

// Round 6
// 763.414 us; speedup vs baseline: 1.0121x; 1.0121x over previous
//
#include <hip/hip_runtime.h>
#include <hip/hip_bf16.h>
#include <stdint.h>
#include <stddef.h>

// B=2, T=2048, D=2048, H=16, DH=128, F=8192, M=B*T=4096
using bf16_t = __hip_bfloat16;
typedef __attribute__((ext_vector_type(8))) short short8;
typedef __attribute__((ext_vector_type(4))) float f32x4;

__device__ __forceinline__ void gload_lds16(const void* g, void* l) {
  __builtin_amdgcn_global_load_lds((const __attribute__((address_space(1))) void*)g,
                                   (__attribute__((address_space(3))) void*)l,
                                   16, 0, 0);
}

// ---------- transpose + f32->bf16 convert: out[N][K] = in[K][N] ----------
__global__ __launch_bounds__(256) void k_transpose_cvt(const float* __restrict__ in,
                                                       bf16_t* __restrict__ out,
                                                       int K, int N) {
  __shared__ float tile[64][65];
  int n0 = blockIdx.x * 64, k0 = blockIdx.y * 64;
  int t = threadIdx.x;
#pragma unroll
  for (int i = 0; i < 16; ++i) {
    int idx = t + i * 256;
    int kk = idx >> 6, nn = idx & 63;
    tile[kk][nn] = in[(size_t)(k0 + kk) * N + n0 + nn];
  }
  __syncthreads();
#pragma unroll
  for (int i = 0; i < 16; ++i) {
    int idx = t + i * 256;
    int nn = idx >> 6, kk = idx & 63;
    out[(size_t)(n0 + nn) * K + k0 + kk] = __float2bfloat16(tile[kk][nn]);
  }
}

// ---------- layernorm f32 -> bf16, one block per row of 2048 ----------
__global__ __launch_bounds__(256) void k_layernorm(const float* __restrict__ x,
                                                   const float* __restrict__ gam,
                                                   const float* __restrict__ bet,
                                                   bf16_t* __restrict__ out) {
  int row = blockIdx.x, t = threadIdx.x;
  const float4* xr = (const float4*)(x + (size_t)row * 2048);
  float4 a = xr[t], b = xr[t + 256];
  float s  = a.x + a.y + a.z + a.w + b.x + b.y + b.z + b.w;
  float s2 = a.x*a.x + a.y*a.y + a.z*a.z + a.w*a.w
           + b.x*b.x + b.y*b.y + b.z*b.z + b.w*b.w;
#pragma unroll
  for (int off = 32; off >= 1; off >>= 1) {
    s  += __shfl_xor(s, off);
    s2 += __shfl_xor(s2, off);
  }
  __shared__ float red[8];
  if ((t & 63) == 0) { red[t >> 6] = s; red[4 + (t >> 6)] = s2; }
  __syncthreads();
  float S  = red[0] + red[1] + red[2] + red[3];
  float S2 = red[4] + red[5] + red[6] + red[7];
  float mu = S * (1.0f / 2048.0f);
  float var = S2 * (1.0f / 2048.0f) - mu * mu;
  float rstd = rsqrtf(var + 1e-6f);
  const float4* gv = (const float4*)gam;
  const float4* bv = (const float4*)bet;
  float4 g1 = gv[t], g2 = gv[t + 256], c1 = bv[t], c2 = bv[t + 256];
  bf16_t* orow = out + (size_t)row * 2048;
  orow[4*t + 0]    = __float2bfloat16((a.x - mu) * rstd * g1.x + c1.x);
  orow[4*t + 1]    = __float2bfloat16((a.y - mu) * rstd * g1.y + c1.y);
  orow[4*t + 2]    = __float2bfloat16((a.z - mu) * rstd * g1.z + c1.z);
  orow[4*t + 3]    = __float2bfloat16((a.w - mu) * rstd * g1.w + c1.w);
  orow[1024 + 4*t + 0] = __float2bfloat16((b.x - mu) * rstd * g2.x + c2.x);
  orow[1024 + 4*t + 1] = __float2bfloat16((b.y - mu) * rstd * g2.y + c2.y);
  orow[1024 + 4*t + 2] = __float2bfloat16((b.z - mu) * rstd * g2.z + c2.z);
  orow[1024 + 4*t + 3] = __float2bfloat16((b.w - mu) * rstd * g2.w + c2.w);
}

// ---------- TLP GEMM: C[M,N] = A[M,K] x Bt[N,K] (bf16), optional split-K ----------
// BM=256, BN=128, BK=32. 256 threads = 4 waves (2M x 2N), per-wave C = 128x64.
// LDS 48KB dbuf + ~210 regs -> 2 blocks/CU: the 2 waves/SIMD belong to DIFFERENT
// blocks (independent barriers) so stalls cross-hide (m97/m114 principle).
// One s_barrier + one lgkmcnt(0) + one vmcnt(0) per K-step; stage of t+1 issued
// at top of iter t (cover = full body). XOR chunk swizzle both sides (read-side
// quarter-phase bank spread). EPI: 0 = bf16+bias ; 1 = bf16+bias+gelu ; 3 = f32 partial.
template <int EPI>
__global__ __launch_bounds__(256, 2) void k_gemm3(const bf16_t* __restrict__ A,
                                                  const bf16_t* __restrict__ Bt,
                                                  const float* __restrict__ bias,
                                                  bf16_t* __restrict__ Cb,
                                                  float* __restrict__ Cf,
                                                  int Ndim, int LDA, int LDB,
                                                  int Kdim, int nkch) {
  __shared__ __align__(16) bf16_t Abuf[2][256 * 32];
  __shared__ __align__(16) bf16_t Bbuf[2][128 * 32];
  int nwg = gridDim.x;
  int orig = blockIdx.x;
  int wg = (orig & 7) * (nwg >> 3) + (orig >> 3);   // bijective XCD swizzle (nwg%8==0)
  int bpc = nwg / nkch;
  int chunk = wg / bpc;
  int rem = wg - chunk * bpc;
  int m0 = (rem & 15) * 256;
  int n0 = (rem >> 4) * 128;
  int tid = threadIdx.x;
  int w = tid >> 6, lane = tid & 63;
  int lr = lane & 15, lk = lane >> 4;
  int wr = w >> 1, wc = w & 1;
  const bf16_t* Ag = A + (size_t)m0 * LDA + (size_t)chunk * Kdim;
  const bf16_t* Bg = Bt + (size_t)n0 * LDB + (size_t)chunk * Kdim;

  f32x4 acc[8][4];
#pragma unroll
  for (int i = 0; i < 8; ++i)
#pragma unroll
    for (int j = 0; j < 4; ++j) acc[i][j] = (f32x4){0.f, 0.f, 0.f, 0.f};
  short8 af[8], bq[4];

  auto stage = [&](int buf, int kt) {
#pragma unroll
    for (int l = 0; l < 4; ++l) {
      int o = l * 256 + tid;
      int row = o >> 2, c = o & 3;
      gload_lds16(Ag + (size_t)row * LDA + kt * 32 + ((c ^ ((row >> 1) & 3)) << 3),
                  &Abuf[buf][o * 8]);
    }
#pragma unroll
    for (int l = 0; l < 2; ++l) {
      int o = l * 256 + tid;
      int row = o >> 2, c = o & 3;
      gload_lds16(Bg + (size_t)row * LDB + kt * 32 + ((c ^ ((row >> 1) & 3)) << 3),
                  &Bbuf[buf][o * 8]);
    }
  };
  auto readfr = [&](int buf) {
#pragma unroll
    for (int mf = 0; mf < 8; ++mf) {
      int row = wr * 128 + mf * 16 + lr;
      int ch = lk ^ ((row >> 1) & 3);
      af[mf] = *(const short8*)&Abuf[buf][row * 32 + ch * 8];
    }
#pragma unroll
    for (int nf = 0; nf < 4; ++nf) {
      int row = wc * 64 + nf * 16 + lr;
      int ch = lk ^ ((row >> 1) & 3);
      bq[nf] = *(const short8*)&Bbuf[buf][row * 32 + ch * 8];
    }
  };
  auto mmac = [&]() {
#pragma unroll
    for (int mf = 0; mf < 8; ++mf)
#pragma unroll
      for (int nf = 0; nf < 4; ++nf)
        acc[mf][nf] = __builtin_amdgcn_mfma_f32_16x16x32_bf16(af[mf], bq[nf], acc[mf][nf], 0, 0, 0);
  };

  const int NT = Kdim >> 5;
  stage(0, 0);
  asm volatile("s_waitcnt vmcnt(0)" ::: "memory");
  asm volatile("s_barrier" ::: "memory");
  for (int t = 0; t < NT - 1; ++t) {
    stage((t & 1) ^ 1, t + 1);         // 6 loads for K-step t+1 (other buffer)
    readfr(t & 1);                      // 12 ds_read_b128 (swizzled)
    asm volatile("s_waitcnt lgkmcnt(0)" ::: "memory");
    __builtin_amdgcn_sched_barrier(0);
    __builtin_amdgcn_s_setprio(1);
    mmac();                             // 32 MFMA
    __builtin_amdgcn_s_setprio(0);
    asm volatile("s_waitcnt vmcnt(0)" ::: "memory");   // stage landed (cover = body)
    asm volatile("s_barrier" ::: "memory");
  }
  readfr((NT - 1) & 1);
  asm volatile("s_waitcnt lgkmcnt(0)" ::: "memory");
  __builtin_amdgcn_sched_barrier(0);
  mmac();

  // epilogue
#pragma unroll
  for (int mf = 0; mf < 8; ++mf) {
#pragma unroll
    for (int nf = 0; nf < 4; ++nf) {
#pragma unroll
      for (int r = 0; r < 4; ++r) {
        int rw = m0 + wr * 128 + mf * 16 + lk * 4 + r;
        int cl = n0 + wc * 64 + nf * 16 + lr;
        float v = acc[mf][nf][r];
        size_t gi = (size_t)rw * Ndim + cl;
        if (EPI == 0) {
          Cb[gi] = __float2bfloat16(v + bias[cl]);
        } else if (EPI == 1) {
          float vv = v + bias[cl];
          float u = vv * (vv * vv * 0.044715f + 1.0f) * 0.7978845608028654f;
          float gl = 0.5f * vv * (1.0f + tanhf(u));
          Cb[gi] = __float2bfloat16(gl);
        } else {
          Cf[(size_t)chunk * 4096 * Ndim + gi] = v;   // raw split-K partial
        }
      }
    }
  }
}

// ---------- split-K finish: out += b2 + P0 + P1 (f32, 4096x2048 = 8388608 elems) ----------
__global__ __launch_bounds__(256) void k_reduce(const float* __restrict__ P,
                                                const float* __restrict__ b2,
                                                float* __restrict__ out) {
  int i = blockIdx.x * 1024 + threadIdx.x * 4;       // 8192 blocks x 256 thr x 4
  float4 p0 = *(const float4*)(P + i);
  float4 p1 = *(const float4*)(P + 8388608 + i);
  float4 bb = *(const float4*)(b2 + (i & 2047));
  float4 o  = *(float4*)(out + i);
  o.x += bb.x + p0.x + p1.x;
  o.y += bb.y + p0.y + p1.y;
  o.z += bb.z + p0.z + p1.z;
  o.w += bb.w + p0.w + p1.w;
  *(float4*)(out + i) = o;
}

// ---------- transpose V slice of qkv into vT[b][h][dh][t] ----------
__global__ __launch_bounds__(256) void k_transpose_v(const bf16_t* __restrict__ qkv,
                                                     bf16_t* __restrict__ vT) {
  __shared__ bf16_t tile[64][72];
  int bid = blockIdx.x;
  int tt = bid & 31;
  int dt = (bid >> 5) & 1;
  int h  = (bid >> 6) & 15;
  int b  = bid >> 10;
  int t0 = tt * 64, d0 = dt * 64;
  int t = threadIdx.x;
  const bf16_t* src = qkv + (size_t)(b * 2048) * 6144 + 4096 + h * 128;
#pragma unroll
  for (int i = 0; i < 16; ++i) {
    int idx = t + i * 256;
    int rr = idx >> 6, cc = idx & 63;          // rr: t-dim, cc: d-dim
    tile[rr][cc] = src[(size_t)(t0 + rr) * 6144 + d0 + cc];
  }
  __syncthreads();
  bf16_t* dst = vT + (size_t)(b * 16 + h) * 128 * 2048;
#pragma unroll
  for (int i = 0; i < 16; ++i) {
    int idx = t + i * 256;
    int rr = idx >> 6, cc = idx & 63;          // rr: d-dim, cc: t-dim
    dst[(size_t)(d0 + rr) * 2048 + t0 + cc] = tile[cc][rr];
  }
}

// ---------- causal flash attention + residual add: out = x + softmax(QK^T/sqrt(dh))V ----------
// One wave owns 32 q-rows (2x16 fragments). KBLK=32. 512 blocks x 4 waves.
// Block j: bh = j&31, cq = j>>5; waves get q-chunks {cq, 63-cq, 31-cq, 32+cq}.
__global__ __launch_bounds__(256, 2) void k_attn(const bf16_t* __restrict__ qkv,
                                                 const bf16_t* __restrict__ vT,
                                                 const float* __restrict__ x,
                                                 float* __restrict__ out) {
  __shared__ __align__(16) bf16_t Pl[4][32][40];   // per-wave P bounce, stride 40
  int j = blockIdx.x;
  int bh = j & 31;
  int cq = j >> 5;                                  // 0..15
  int b = bh >> 4, h = bh & 15;
  int w = threadIdx.x >> 6, lane = threadIdx.x & 63;
  int lr = lane & 15, lk = lane >> 4;
  int c = (w == 0) ? cq : (w == 1) ? (63 - cq) : (w == 2) ? (31 - cq) : (32 + cq);
  int q0 = c * 32;                                  // this wave's 32 q-rows
  const bf16_t* qb = qkv + (size_t)(b * 2048) * 6144 + h * 128;
  const bf16_t* kb = qb + 2048;
  const bf16_t* vb = vT + (size_t)(b * 16 + h) * 128 * 2048;
  short8 qf[2][4];
#pragma unroll
  for (int qg = 0; qg < 2; ++qg)
#pragma unroll
    for (int d4 = 0; d4 < 4; ++d4)
      qf[qg][d4] = *(const short8*)(qb + (size_t)(q0 + qg * 16 + lr) * 6144 + d4 * 32 + lk * 8);
  float m[2][4], l[2][4];
#pragma unroll
  for (int qg = 0; qg < 2; ++qg)
#pragma unroll
    for (int r = 0; r < 4; ++r) { m[qg][r] = -1e30f; l[qg][r] = 0.f; }
  f32x4 o[2][8] = {};
  int nkt = c + 1;
  const float sc = 0.08838834764831845f;           // 1/sqrt(128)
  for (int kt = 0; kt < nkt; ++kt) {
    int tk0 = kt * 32;
    short8 vf[8];
#pragma unroll
    for (int d8 = 0; d8 < 8; ++d8)
      vf[d8] = *(const short8*)(vb + (size_t)(d8 * 16 + lr) * 2048 + tk0 + lk * 8);
    short8 kf[2][4];
#pragma unroll
    for (int nt = 0; nt < 2; ++nt)
#pragma unroll
      for (int d4 = 0; d4 < 4; ++d4)
        kf[nt][d4] = *(const short8*)(kb + (size_t)(tk0 + nt * 16 + lr) * 6144 + d4 * 32 + lk * 8);
    f32x4 s[2][2] = {};
#pragma unroll
    for (int d4 = 0; d4 < 4; ++d4)
#pragma unroll
      for (int qg = 0; qg < 2; ++qg)
#pragma unroll
        for (int nt = 0; nt < 2; ++nt)
          s[qg][nt] = __builtin_amdgcn_mfma_f32_16x16x32_bf16(qf[qg][d4], kf[nt][d4], s[qg][nt], 0, 0, 0);
#pragma unroll
    for (int qg = 0; qg < 2; ++qg) {
      float sv[2][4], mt[4];
#pragma unroll
      for (int r = 0; r < 4; ++r) {
        int qr = q0 + qg * 16 + lk * 4 + r;
#pragma unroll
        for (int nt = 0; nt < 2; ++nt) {
          float v = s[qg][nt][r] * sc;
          int kc = tk0 + nt * 16 + lr;
          sv[nt][r] = (kc > qr) ? -1e30f : v;
        }
        mt[r] = fmaxf(sv[0][r], sv[1][r]);
      }
#pragma unroll
      for (int off = 1; off < 16; off <<= 1)
#pragma unroll
        for (int r = 0; r < 4; ++r) mt[r] = fmaxf(mt[r], __shfl_xor(mt[r], off));
      float alpha[4], rs[4];
#pragma unroll
      for (int r = 0; r < 4; ++r) {
        float mn = fmaxf(m[qg][r], mt[r]);
        alpha[r] = __expf(m[qg][r] - mn);
        m[qg][r] = mn;
      }
#pragma unroll
      for (int r = 0; r < 4; ++r) {
        float p0 = __expf(sv[0][r] - m[qg][r]);
        float p1 = __expf(sv[1][r] - m[qg][r]);
        rs[r] = p0 + p1;
        Pl[w][qg * 16 + lk * 4 + r][lr]      = __float2bfloat16(p0);
        Pl[w][qg * 16 + lk * 4 + r][16 + lr] = __float2bfloat16(p1);
      }
#pragma unroll
      for (int off = 1; off < 16; off <<= 1)
#pragma unroll
        for (int r = 0; r < 4; ++r) rs[r] += __shfl_xor(rs[r], off);
#pragma unroll
      for (int r = 0; r < 4; ++r) l[qg][r] = l[qg][r] * alpha[r] + rs[r];
#pragma unroll
      for (int d8 = 0; d8 < 8; ++d8)
#pragma unroll
        for (int r = 0; r < 4; ++r) o[qg][d8][r] *= alpha[r];
    }
    asm volatile("s_waitcnt lgkmcnt(0)" ::: "memory");
    short8 pf[2];
#pragma unroll
    for (int qg = 0; qg < 2; ++qg)
      pf[qg] = *(const short8*)(&Pl[w][qg * 16 + lr][lk * 8]);
#pragma unroll
    for (int d8 = 0; d8 < 8; ++d8)
#pragma unroll
      for (int qg = 0; qg < 2; ++qg)
        o[qg][d8] = __builtin_amdgcn_mfma_f32_16x16x32_bf16(pf[qg], vf[d8], o[qg][d8], 0, 0, 0);
  }
#pragma unroll
  for (int qg = 0; qg < 2; ++qg)
#pragma unroll
    for (int d8 = 0; d8 < 8; ++d8)
#pragma unroll
      for (int r = 0; r < 4; ++r) {
        int qr = q0 + qg * 16 + lk * 4 + r;
        int cl = h * 128 + d8 * 16 + lr;
        size_t gi = (size_t)(b * 2048 + qr) * 2048 + cl;
        out[gi] = x[gi] + o[qg][d8][r] / l[qg][r];
      }
}

extern "C" void kernel_launch(void* const* d_in, const int* in_sizes, int n_in,
                              void* d_out, int out_size, void* d_ws, size_t ws_size,
                              hipStream_t stream) {
  const float* x    = (const float*)d_in[0];
  const float* ln1s = (const float*)d_in[1];
  const float* ln1b = (const float*)d_in[2];
  const float* wqkv = (const float*)d_in[3];
  const float* bqkv = (const float*)d_in[4];
  const float* ln2s = (const float*)d_in[5];
  const float* ln2b = (const float*)d_in[6];
  const float* w1   = (const float*)d_in[7];
  const float* b1   = (const float*)d_in[8];
  const float* w2   = (const float*)d_in[9];
  const float* b2   = (const float*)d_in[10];
  float* out = (float*)d_out;
  char* ws = (char*)d_ws;

  // ws layout (bytes); r/vT share region 0 (disjoint lifetimes), wqkvT aliases h,
  // split-K partials P (64MB f32) alias r+qkv (both dead by MLP2 time).
  bf16_t* r     = (bf16_t*)(ws + 0);              // 16,777,216  [4096][2048]
  bf16_t* vT    = (bf16_t*)(ws + 0);              // same region [2][16][128][2048]
  float*  part  = (float*)(ws + 0);               // 67,108,864  [2][4096][2048] f32
  bf16_t* qkv   = (bf16_t*)(ws + 16777216);       // 50,331,648  [4096][6144]
  bf16_t* w1T   = (bf16_t*)(ws + 67108864);       // 33,554,432  [8192][2048]
  bf16_t* w2T   = (bf16_t*)(ws + 100663296);      // 33,554,432  [2048][8192]
  bf16_t* h     = (bf16_t*)(ws + 134217728);      // 67,108,864  [4096][8192]
  bf16_t* wqkvT = (bf16_t*)(ws + 134217728);      // 25,165,824  [6144][2048] (dead before h)
  // total required: 201,326,592 bytes

  // weight transposes (f32 [K][N] -> bf16 [N][K])
  k_transpose_cvt<<<dim3(96, 32),  256, 0, stream>>>(wqkv, wqkvT, 2048, 6144);
  k_transpose_cvt<<<dim3(128, 32), 256, 0, stream>>>(w1,   w1T,   2048, 8192);
  k_transpose_cvt<<<dim3(32, 128), 256, 0, stream>>>(w2,   w2T,   8192, 2048);
  // LN1
  k_layernorm<<<4096, 256, 0, stream>>>(x, ln1s, ln1b, r);
  // QKV: M=4096,N=6144,K=2048 -> 16 x 48 = 768 blocks (2/CU resident, 1.5 fills)
  k_gemm3<0><<<768, 256, 0, stream>>>(r, wqkvT, bqkv, qkv, nullptr, 6144, 2048, 2048, 2048, 1);
  // V transpose for PV operand
  k_transpose_v<<<2048, 256, 0, stream>>>(qkv, vT);
  // attention + residual (writes every element of d_out)
  k_attn<<<512, 256, 0, stream>>>(qkv, vT, x, out);
  // LN2 on x2 = d_out
  k_layernorm<<<4096, 256, 0, stream>>>(out, ln2s, ln2b, r);
  // MLP1: M=4096,N=8192,K=2048 -> 16 x 64 = 1024 blocks
  k_gemm3<1><<<1024, 256, 0, stream>>>(r, w1T, b1, h, nullptr, 8192, 2048, 2048, 2048, 1);
  // MLP2 split-K=2: per chunk K=4096, 16 x 16 = 256 blocks, x2 = 512 (2/CU exact)
  k_gemm3<3><<<512, 256, 0, stream>>>(h, w2T, nullptr, nullptr, part, 2048, 8192, 8192, 4096, 2);
  // finish: out += b2 + P0 + P1 (8,388,608 elements -> 8192 blocks)
  k_reduce<<<8192, 256, 0, stream>>>(part, b2, out);
}

// Round 8
// 685.344 us; speedup vs baseline: 1.1274x; 1.1139x over previous
//
#include <hip/hip_runtime.h>
#include <hip/hip_bf16.h>
#include <stdint.h>
#include <stddef.h>

// B=2, T=2048, D=2048, H=16, DH=128, F=8192, M=B*T=4096
using bf16_t = __hip_bfloat16;
typedef __attribute__((ext_vector_type(8))) short short8;
typedef __attribute__((ext_vector_type(4))) float f32x4;

__device__ __forceinline__ void gload_lds16(const void* g, void* l) {
  __builtin_amdgcn_global_load_lds((const __attribute__((address_space(1))) void*)g,
                                   (__attribute__((address_space(3))) void*)l,
                                   16, 0, 0);
}

// ---------- transpose + f32->bf16 convert: out[N][K] = in[K][N] ----------
__global__ __launch_bounds__(256) void k_transpose_cvt(const float* __restrict__ in,
                                                       bf16_t* __restrict__ out,
                                                       int K, int N) {
  __shared__ float tile[64][65];
  int n0 = blockIdx.x * 64, k0 = blockIdx.y * 64;
  int t = threadIdx.x;
#pragma unroll
  for (int i = 0; i < 16; ++i) {
    int idx = t + i * 256;
    int kk = idx >> 6, nn = idx & 63;
    tile[kk][nn] = in[(size_t)(k0 + kk) * N + n0 + nn];
  }
  __syncthreads();
#pragma unroll
  for (int i = 0; i < 16; ++i) {
    int idx = t + i * 256;
    int nn = idx >> 6, kk = idx & 63;
    out[(size_t)(n0 + nn) * K + k0 + kk] = __float2bfloat16(tile[kk][nn]);
  }
}

// ---------- layernorm f32 -> bf16, one block per row of 2048 ----------
__global__ __launch_bounds__(256) void k_layernorm(const float* __restrict__ x,
                                                   const float* __restrict__ gam,
                                                   const float* __restrict__ bet,
                                                   bf16_t* __restrict__ out) {
  int row = blockIdx.x, t = threadIdx.x;
  const float4* xr = (const float4*)(x + (size_t)row * 2048);
  float4 a = xr[t], b = xr[t + 256];
  float s  = a.x + a.y + a.z + a.w + b.x + b.y + b.z + b.w;
  float s2 = a.x*a.x + a.y*a.y + a.z*a.z + a.w*a.w
           + b.x*b.x + b.y*b.y + b.z*b.z + b.w*b.w;
#pragma unroll
  for (int off = 32; off >= 1; off >>= 1) {
    s  += __shfl_xor(s, off);
    s2 += __shfl_xor(s2, off);
  }
  __shared__ float red[8];
  if ((t & 63) == 0) { red[t >> 6] = s; red[4 + (t >> 6)] = s2; }
  __syncthreads();
  float S  = red[0] + red[1] + red[2] + red[3];
  float S2 = red[4] + red[5] + red[6] + red[7];
  float mu = S * (1.0f / 2048.0f);
  float var = S2 * (1.0f / 2048.0f) - mu * mu;
  float rstd = rsqrtf(var + 1e-6f);
  const float4* gv = (const float4*)gam;
  const float4* bv = (const float4*)bet;
  float4 g1 = gv[t], g2 = gv[t + 256], c1 = bv[t], c2 = bv[t + 256];
  bf16_t* orow = out + (size_t)row * 2048;
  orow[4*t + 0]    = __float2bfloat16((a.x - mu) * rstd * g1.x + c1.x);
  orow[4*t + 1]    = __float2bfloat16((a.y - mu) * rstd * g1.y + c1.y);
  orow[4*t + 2]    = __float2bfloat16((a.z - mu) * rstd * g1.z + c1.z);
  orow[4*t + 3]    = __float2bfloat16((a.w - mu) * rstd * g1.w + c1.w);
  orow[1024 + 4*t + 0] = __float2bfloat16((b.x - mu) * rstd * g2.x + c2.x);
  orow[1024 + 4*t + 1] = __float2bfloat16((b.y - mu) * rstd * g2.y + c2.y);
  orow[1024 + 4*t + 2] = __float2bfloat16((b.z - mu) * rstd * g2.z + c2.z);
  orow[1024 + 4*t + 3] = __float2bfloat16((b.w - mu) * rstd * g2.w + c2.w);
}

// ---------- deep-pipelined TLP GEMM: C[M,N] = A[M,K] x Bt[N,K] (bf16) ----------
// BM=256, BN=128, BK=32. 256 threads = 4 waves (2M x 2N), per-wave C = 128x64.
// LDS 64KB/block (A: 3 x 16KB bufs, B: 2 x 8KB bufs) -> 2 blocks/CU (cross-block TLP).
// Body t: issue B(t+1) then A(t+2); ds_read bufs of t; lgkm0; 32 MFMA; vmcnt(4)
// [in-order retire => A(t+1),B(t+1) landed, A(t+2) still in flight]; one barrier.
// A-cover = 2 bodies (~700cy >= L3), B-cover = 1 body (weights L2-hot). All ds/global
// addresses strength-reduced: persistent pointers +64B/step, uniform buf-base ints.
// R8 FIX: prologue must stage B(0) into the READ buffer (0), not b_wr (8192) —
// R7 read uninitialized LDS on K-step 0 -> NaN.
// EPI: 0 = bf16+bias ; 1 = bf16+bias+gelu ; 3 = f32 raw partial (split-K).
template <int EPI>
__global__ __launch_bounds__(256, 2) void k_gemm4(const bf16_t* __restrict__ A,
                                                  const bf16_t* __restrict__ Bt,
                                                  const float* __restrict__ bias,
                                                  bf16_t* __restrict__ Cb,
                                                  float* __restrict__ Cf,
                                                  int Ndim, int LDA, int LDB,
                                                  int Kdim, int nkch) {
  __shared__ __align__(16) char lds[65536];      // [0,48K): A bufs, [48K,64K): B bufs
  int nwg = gridDim.x;
  int orig = blockIdx.x;
  int wg = (orig & 7) * (nwg >> 3) + (orig >> 3);   // bijective XCD swizzle (nwg%8==0)
  int bpc = nwg / nkch;
  int chunk = wg / bpc;
  int rem = wg - chunk * bpc;
  int m0 = (rem & 15) * 256;
  int n0 = (rem >> 4) * 128;
  int tid = threadIdx.x;
  int w = tid >> 6, lane = tid & 63;
  int lr = lane & 15, lk = lane >> 4;
  int wr = w >> 1, wc = w & 1;

  // ---- persistent global staging pointers (advance +32 elems = 64B per K-step) ----
  int srow = tid >> 2;                      // 0..63
  int scol = ((tid & 3) ^ ((tid >> 3) & 3)) << 3;   // swizzled source col (elems)
  const bf16_t* Ag = A + (size_t)m0 * LDA + (size_t)chunk * Kdim;
  const bf16_t* Bg = Bt + (size_t)n0 * LDB + (size_t)chunk * Kdim;
  const bf16_t* pA0 = Ag + (size_t)(srow)       * LDA + scol;
  const bf16_t* pA1 = Ag + (size_t)(srow + 64)  * LDA + scol;
  const bf16_t* pA2 = Ag + (size_t)(srow + 128) * LDA + scol;
  const bf16_t* pA3 = Ag + (size_t)(srow + 192) * LDA + scol;
  const bf16_t* pB0 = Bg + (size_t)(srow)       * LDB + scol;
  const bf16_t* pB1 = Bg + (size_t)(srow + 64)  * LDB + scol;
  int dst = tid * 16;                       // per-thread LDS dst byte offset in buf

  // ---- loop-invariant swizzled ds_read byte offsets ----
  int ch = (lk ^ ((lr >> 1) & 3)) * 16;
  int aoff[8], boff[4];
#pragma unroll
  for (int mf = 0; mf < 8; ++mf) aoff[mf] = (wr * 128 + mf * 16 + lr) * 64 + ch;
#pragma unroll
  for (int nf = 0; nf < 4; ++nf) boff[nf] = 49152 + (wc * 64 + nf * 16 + lr) * 64 + ch;

  f32x4 acc[8][4];
#pragma unroll
  for (int i = 0; i < 8; ++i)
#pragma unroll
    for (int j = 0; j < 4; ++j) acc[i][j] = (f32x4){0.f, 0.f, 0.f, 0.f};
  short8 af[8], bq[4];

#define STAGE_A()  do { \
    gload_lds16(pA0, lds + a_wr + dst);          \
    gload_lds16(pA1, lds + a_wr + 4096 + dst);   \
    gload_lds16(pA2, lds + a_wr + 8192 + dst);   \
    gload_lds16(pA3, lds + a_wr + 12288 + dst);  \
    pA0 += 32; pA1 += 32; pA2 += 32; pA3 += 32; } while (0)
#define STAGE_B()  do { \
    gload_lds16(pB0, lds + 49152 + b_wr + dst);        \
    gload_lds16(pB1, lds + 49152 + b_wr + 4096 + dst); \
    pB0 += 32; pB1 += 32; } while (0)
#define READ_FR()  do { \
    _Pragma("unroll") for (int mf = 0; mf < 8; ++mf) \
      af[mf] = *(const short8*)(lds + a_rd + aoff[mf]); \
    _Pragma("unroll") for (int nf = 0; nf < 4; ++nf) \
      bq[nf] = *(const short8*)(lds + b_rd + boff[nf]); } while (0)
#define MMAC()  do { \
    _Pragma("unroll") for (int mf = 0; mf < 8; ++mf) \
      _Pragma("unroll") for (int nf = 0; nf < 4; ++nf) \
        acc[mf][nf] = __builtin_amdgcn_mfma_f32_16x16x32_bf16(af[mf], bq[nf], acc[mf][nf], 0, 0, 0); } while (0)
#define LGKM0()  do { asm volatile("s_waitcnt lgkmcnt(0)" ::: "memory"); __builtin_amdgcn_sched_barrier(0); } while (0)
#define VM(N)    asm volatile("s_waitcnt vmcnt(%0)" :: "i"(N) : "memory")
#define BARRIER() asm volatile("s_barrier" ::: "memory")

  int a_rd = 0, a_wr = 32768;               // A bufs cycle {0,16384,32768}
  int b_rd = 0, b_wr = 8192;                // B bufs toggle {0,8192}
  const int NT = Kdim >> 5;

  // prologue: A(0)->buf0, B(0)->buf0 (the READ buffer!), A(1)->buf1.
  // in-order queue => vmcnt(4) retires exactly A(0)+B(0); A(1) stays in flight.
  { int sva = a_wr, svb = b_wr;
    a_wr = 0;     STAGE_A();
    b_wr = 0;     STAGE_B();
    a_wr = 16384; STAGE_A();
    a_wr = sva;   b_wr = svb; }
  VM(4);
  BARRIER();

  for (int t = 0; t < NT - 2; ++t) {
    STAGE_B();                              // B(t+1) -> b_wr
    STAGE_A();                              // A(t+2) -> a_wr
    READ_FR();
    LGKM0();
    __builtin_amdgcn_s_setprio(1);
    MMAC();
    __builtin_amdgcn_s_setprio(0);
    VM(4);                                  // A(t+1),B(t+1) landed; A(t+2) in flight
    BARRIER();
    int fr = a_rd; a_rd = (a_rd == 32768) ? 0 : a_rd + 16384; a_wr = fr;
    fr = b_rd; b_rd = b_wr; b_wr = fr;
  }
  {                                         // body NT-2: stage B(NT-1) only
    STAGE_B();
    READ_FR();
    LGKM0();
    __builtin_amdgcn_s_setprio(1);
    MMAC();
    __builtin_amdgcn_s_setprio(0);
    VM(0);
    BARRIER();
    a_rd = (a_rd == 32768) ? 0 : a_rd + 16384;
    b_rd = b_wr;
  }
  {                                         // body NT-1: compute only
    READ_FR();
    LGKM0();
    MMAC();
  }
#undef STAGE_A
#undef STAGE_B
#undef READ_FR
#undef MMAC
#undef LGKM0
#undef VM
#undef BARRIER

  // epilogue
#pragma unroll
  for (int mf = 0; mf < 8; ++mf) {
#pragma unroll
    for (int nf = 0; nf < 4; ++nf) {
#pragma unroll
      for (int r = 0; r < 4; ++r) {
        int rw = m0 + wr * 128 + mf * 16 + lk * 4 + r;
        int cl = n0 + wc * 64 + nf * 16 + lr;
        float v = acc[mf][nf][r];
        size_t gi = (size_t)rw * Ndim + cl;
        if (EPI == 0) {
          Cb[gi] = __float2bfloat16(v + bias[cl]);
        } else if (EPI == 1) {
          float vv = v + bias[cl];
          float u = vv * (vv * vv * 0.044715f + 1.0f) * 0.7978845608028654f;
          float gl = 0.5f * vv * (1.0f + tanhf(u));
          Cb[gi] = __float2bfloat16(gl);
        } else {
          Cf[(size_t)chunk * 4096 * Ndim + gi] = v;   // raw split-K partial
        }
      }
    }
  }
}

// ---------- split-K finish: out += b2 + P0 + P1 (f32, 4096x2048 = 8388608 elems) ----------
__global__ __launch_bounds__(256) void k_reduce(const float* __restrict__ P,
                                                const float* __restrict__ b2,
                                                float* __restrict__ out) {
  int i = blockIdx.x * 1024 + threadIdx.x * 4;       // 8192 blocks x 256 thr x 4
  float4 p0 = *(const float4*)(P + i);
  float4 p1 = *(const float4*)(P + 8388608 + i);
  float4 bb = *(const float4*)(b2 + (i & 2047));
  float4 o  = *(float4*)(out + i);
  o.x += bb.x + p0.x + p1.x;
  o.y += bb.y + p0.y + p1.y;
  o.z += bb.z + p0.z + p1.z;
  o.w += bb.w + p0.w + p1.w;
  *(float4*)(out + i) = o;
}

// ---------- transpose V slice of qkv into vT[b][h][dh][t] ----------
__global__ __launch_bounds__(256) void k_transpose_v(const bf16_t* __restrict__ qkv,
                                                     bf16_t* __restrict__ vT) {
  __shared__ bf16_t tile[64][72];
  int bid = blockIdx.x;
  int tt = bid & 31;
  int dt = (bid >> 5) & 1;
  int h  = (bid >> 6) & 15;
  int b  = bid >> 10;
  int t0 = tt * 64, d0 = dt * 64;
  int t = threadIdx.x;
  const bf16_t* src = qkv + (size_t)(b * 2048) * 6144 + 4096 + h * 128;
#pragma unroll
  for (int i = 0; i < 16; ++i) {
    int idx = t + i * 256;
    int rr = idx >> 6, cc = idx & 63;          // rr: t-dim, cc: d-dim
    tile[rr][cc] = src[(size_t)(t0 + rr) * 6144 + d0 + cc];
  }
  __syncthreads();
  bf16_t* dst = vT + (size_t)(b * 16 + h) * 128 * 2048;
#pragma unroll
  for (int i = 0; i < 16; ++i) {
    int idx = t + i * 256;
    int rr = idx >> 6, cc = idx & 63;          // rr: d-dim, cc: t-dim
    dst[(size_t)(d0 + rr) * 2048 + t0 + cc] = tile[cc][rr];
  }
}

// ---------- causal flash attention + residual add: out = x + softmax(QK^T/sqrt(dh))V ----------
// One wave owns 32 q-rows (2x16 fragments). KBLK=32. 512 blocks x 4 waves.
// Block j: bh = j&31, cq = j>>5; waves get q-chunks {cq, 63-cq, 31-cq, 32+cq}.
__global__ __launch_bounds__(256, 2) void k_attn(const bf16_t* __restrict__ qkv,
                                                 const bf16_t* __restrict__ vT,
                                                 const float* __restrict__ x,
                                                 float* __restrict__ out) {
  __shared__ __align__(16) bf16_t Pl[4][32][40];   // per-wave P bounce, stride 40
  int j = blockIdx.x;
  int bh = j & 31;
  int cq = j >> 5;                                  // 0..15
  int b = bh >> 4, h = bh & 15;
  int w = threadIdx.x >> 6, lane = threadIdx.x & 63;
  int lr = lane & 15, lk = lane >> 4;
  int c = (w == 0) ? cq : (w == 1) ? (63 - cq) : (w == 2) ? (31 - cq) : (32 + cq);
  int q0 = c * 32;                                  // this wave's 32 q-rows
  const bf16_t* qb = qkv + (size_t)(b * 2048) * 6144 + h * 128;
  const bf16_t* kb = qb + 2048;
  const bf16_t* vb = vT + (size_t)(b * 16 + h) * 128 * 2048;
  short8 qf[2][4];
#pragma unroll
  for (int qg = 0; qg < 2; ++qg)
#pragma unroll
    for (int d4 = 0; d4 < 4; ++d4)
      qf[qg][d4] = *(const short8*)(qb + (size_t)(q0 + qg * 16 + lr) * 6144 + d4 * 32 + lk * 8);
  float m[2][4], l[2][4];
#pragma unroll
  for (int qg = 0; qg < 2; ++qg)
#pragma unroll
    for (int r = 0; r < 4; ++r) { m[qg][r] = -1e30f; l[qg][r] = 0.f; }
  f32x4 o[2][8] = {};
  int nkt = c + 1;
  const float sc = 0.08838834764831845f;           // 1/sqrt(128)
  for (int kt = 0; kt < nkt; ++kt) {
    int tk0 = kt * 32;
    short8 vf[8];
#pragma unroll
    for (int d8 = 0; d8 < 8; ++d8)
      vf[d8] = *(const short8*)(vb + (size_t)(d8 * 16 + lr) * 2048 + tk0 + lk * 8);
    short8 kf[2][4];
#pragma unroll
    for (int nt = 0; nt < 2; ++nt)
#pragma unroll
      for (int d4 = 0; d4 < 4; ++d4)
        kf[nt][d4] = *(const short8*)(kb + (size_t)(tk0 + nt * 16 + lr) * 6144 + d4 * 32 + lk * 8);
    f32x4 s[2][2] = {};
#pragma unroll
    for (int d4 = 0; d4 < 4; ++d4)
#pragma unroll
      for (int qg = 0; qg < 2; ++qg)
#pragma unroll
        for (int nt = 0; nt < 2; ++nt)
          s[qg][nt] = __builtin_amdgcn_mfma_f32_16x16x32_bf16(qf[qg][d4], kf[nt][d4], s[qg][nt], 0, 0, 0);
#pragma unroll
    for (int qg = 0; qg < 2; ++qg) {
      float sv[2][4], mt[4];
#pragma unroll
      for (int r = 0; r < 4; ++r) {
        int qr = q0 + qg * 16 + lk * 4 + r;
#pragma unroll
        for (int nt = 0; nt < 2; ++nt) {
          float v = s[qg][nt][r] * sc;
          int kc = tk0 + nt * 16 + lr;
          sv[nt][r] = (kc > qr) ? -1e30f : v;
        }
        mt[r] = fmaxf(sv[0][r], sv[1][r]);
      }
#pragma unroll
      for (int off = 1; off < 16; off <<= 1)
#pragma unroll
        for (int r = 0; r < 4; ++r) mt[r] = fmaxf(mt[r], __shfl_xor(mt[r], off));
      float alpha[4], rs[4];
#pragma unroll
      for (int r = 0; r < 4; ++r) {
        float mn = fmaxf(m[qg][r], mt[r]);
        alpha[r] = __expf(m[qg][r] - mn);
        m[qg][r] = mn;
      }
#pragma unroll
      for (int r = 0; r < 4; ++r) {
        float p0 = __expf(sv[0][r] - m[qg][r]);
        float p1 = __expf(sv[1][r] - m[qg][r]);
        rs[r] = p0 + p1;
        Pl[w][qg * 16 + lk * 4 + r][lr]      = __float2bfloat16(p0);
        Pl[w][qg * 16 + lk * 4 + r][16 + lr] = __float2bfloat16(p1);
      }
#pragma unroll
      for (int off = 1; off < 16; off <<= 1)
#pragma unroll
        for (int r = 0; r < 4; ++r) rs[r] += __shfl_xor(rs[r], off);
#pragma unroll
      for (int r = 0; r < 4; ++r) l[qg][r] = l[qg][r] * alpha[r] + rs[r];
#pragma unroll
      for (int d8 = 0; d8 < 8; ++d8)
#pragma unroll
        for (int r = 0; r < 4; ++r) o[qg][d8][r] *= alpha[r];
    }
    asm volatile("s_waitcnt lgkmcnt(0)" ::: "memory");
    short8 pf[2];
#pragma unroll
    for (int qg = 0; qg < 2; ++qg)
      pf[qg] = *(const short8*)(&Pl[w][qg * 16 + lr][lk * 8]);
#pragma unroll
    for (int d8 = 0; d8 < 8; ++d8)
#pragma unroll
      for (int qg = 0; qg < 2; ++qg)
        o[qg][d8] = __builtin_amdgcn_mfma_f32_16x16x32_bf16(pf[qg], vf[d8], o[qg][d8], 0, 0, 0);
  }
#pragma unroll
  for (int qg = 0; qg < 2; ++qg)
#pragma unroll
    for (int d8 = 0; d8 < 8; ++d8)
#pragma unroll
      for (int r = 0; r < 4; ++r) {
        int qr = q0 + qg * 16 + lk * 4 + r;
        int cl = h * 128 + d8 * 16 + lr;
        size_t gi = (size_t)(b * 2048 + qr) * 2048 + cl;
        out[gi] = x[gi] + o[qg][d8][r] / l[qg][r];
      }
}

extern "C" void kernel_launch(void* const* d_in, const int* in_sizes, int n_in,
                              void* d_out, int out_size, void* d_ws, size_t ws_size,
                              hipStream_t stream) {
  const float* x    = (const float*)d_in[0];
  const float* ln1s = (const float*)d_in[1];
  const float* ln1b = (const float*)d_in[2];
  const float* wqkv = (const float*)d_in[3];
  const float* bqkv = (const float*)d_in[4];
  const float* ln2s = (const float*)d_in[5];
  const float* ln2b = (const float*)d_in[6];
  const float* w1   = (const float*)d_in[7];
  const float* b1   = (const float*)d_in[8];
  const float* w2   = (const float*)d_in[9];
  const float* b2   = (const float*)d_in[10];
  float* out = (float*)d_out;
  char* ws = (char*)d_ws;

  // ws layout (bytes); r/vT share region 0 (disjoint lifetimes), wqkvT aliases h,
  // split-K partials P (64MB f32) alias r+qkv (both dead by MLP2 time).
  bf16_t* r     = (bf16_t*)(ws + 0);              // 16,777,216  [4096][2048]
  bf16_t* vT    = (bf16_t*)(ws + 0);              // same region [2][16][128][2048]
  float*  part  = (float*)(ws + 0);               // 67,108,864  [2][4096][2048] f32
  bf16_t* qkv   = (bf16_t*)(ws + 16777216);       // 50,331,648  [4096][6144]
  bf16_t* w1T   = (bf16_t*)(ws + 67108864);       // 33,554,432  [8192][2048]
  bf16_t* w2T   = (bf16_t*)(ws + 100663296);      // 33,554,432  [2048][8192]
  bf16_t* h     = (bf16_t*)(ws + 134217728);      // 67,108,864  [4096][8192]
  bf16_t* wqkvT = (bf16_t*)(ws + 134217728);      // 25,165,824  [6144][2048] (dead before h)
  // total required: 201,326,592 bytes

  // weight transposes (f32 [K][N] -> bf16 [N][K])
  k_transpose_cvt<<<dim3(96, 32),  256, 0, stream>>>(wqkv, wqkvT, 2048, 6144);
  k_transpose_cvt<<<dim3(128, 32), 256, 0, stream>>>(w1,   w1T,   2048, 8192);
  k_transpose_cvt<<<dim3(32, 128), 256, 0, stream>>>(w2,   w2T,   8192, 2048);
  // LN1
  k_layernorm<<<4096, 256, 0, stream>>>(x, ln1s, ln1b, r);
  // QKV: M=4096,N=6144,K=2048 -> 16 x 48 = 768 blocks
  k_gemm4<0><<<768, 256, 0, stream>>>(r, wqkvT, bqkv, qkv, nullptr, 6144, 2048, 2048, 2048, 1);
  // V transpose for PV operand
  k_transpose_v<<<2048, 256, 0, stream>>>(qkv, vT);
  // attention + residual (writes every element of d_out)
  k_attn<<<512, 256, 0, stream>>>(qkv, vT, x, out);
  // LN2 on x2 = d_out
  k_layernorm<<<4096, 256, 0, stream>>>(out, ln2s, ln2b, r);
  // MLP1: M=4096,N=8192,K=2048 -> 16 x 64 = 1024 blocks (2 full rounds)
  k_gemm4<1><<<1024, 256, 0, stream>>>(r, w1T, b1, h, nullptr, 8192, 2048, 2048, 2048, 1);
  // MLP2 split-K=2: per chunk K=4096, 16 x 16 = 256 blocks, x2 = 512 (1 round exact)
  k_gemm4<3><<<512, 256, 0, stream>>>(h, w2T, nullptr, nullptr, part, 2048, 8192, 8192, 4096, 2);
  // finish: out += b2 + P0 + P1 (8,388,608 elements -> 8192 blocks)
  k_reduce<<<8192, 256, 0, stream>>>(part, b2, out);
}